// Round 16
// baseline (87.922 us; speedup 1.0000x reference)
//
#include <hip/hip_runtime.h>
#include <hip/hip_bf16.h>

typedef __attribute__((ext_vector_type(4))) float f32x4;
typedef __attribute__((ext_vector_type(8))) short s16x8;
typedef __attribute__((ext_vector_type(4))) unsigned int u32x4;

#define NODES 100000
#define SROW (NODES + 1)   // +1 zero row per slice: predication-free gathers
#define DIN 256
#define DOUT 128
#define NSLICE 2
#define SLICE_CH 64        // h_s[slice][SROW][64] bf16 = 12.8 MB/slice
#define EW 136             // epilogue LDS row stride (128 + 8 pad shorts)

static __device__ inline unsigned short f2bf(float f) {
    __hip_bfloat16 h = __float2bfloat16(f);
    return __builtin_bit_cast(unsigned short, h);
}
static __device__ inline float lo2f(unsigned int v) {  // low bf16 -> f32
    return __builtin_bit_cast(float, v << 16);
}
static __device__ inline float hi2f(unsigned int v) {  // high bf16 -> f32
    return __builtin_bit_cast(float, v & 0xffff0000u);
}

// async global->LDS, 16B per lane. Dest must be wave-uniform; source is
// per-lane (pre-swizzled source = rule-21 both-sides involution).
#define GLOAD16(GP, LP) \
    __builtin_amdgcn_global_load_lds( \
        (const __attribute__((address_space(1))) void*)(GP), \
        (__attribute__((address_space(3))) void*)(LP), 16, 0, 0)

// ---------------- prep: W fp32 -> bf16 ; inv_deg ; zero rows ----------------
__global__ __launch_bounds__(256) void gcn_prep(const float* __restrict__ W,
                                                const int* __restrict__ ptr,
                                                unsigned short* __restrict__ wsW,
                                                float* __restrict__ inv_deg,
                                                unsigned short* __restrict__ h_s) {
    int t = blockIdx.x * 256 + threadIdx.x;
    if (t < DOUT * DIN) wsW[t] = f2bf(W[t]);
    if (t < NODES) {
        int d = ptr[t + 1] - ptr[t];
        inv_deg[t] = d > 0 ? 1.0f / (float)d : 0.0f;
    }
    if (t < NSLICE * SLICE_CH)  // zero row (node index NODES) of each slice
        h_s[(long)(t >> 6) * ((long)SROW * SLICE_CH) + (long)NODES * SLICE_CH + (t & 63)] = 0;
}

// ---------------- GEMM: h_s[slice][SROW][64] (bf16) = x @ W.T ---------------
// (R14/R15 structure, unchanged: global_load_lds staging, B staged first
// (L2-hot, retires under A's HBM latency), pre-swizzled source + swizzled
// fragment reads, involution byte16-slot ^= ((row&7)<<4). ~24-26us measured.)
__global__ __launch_bounds__(256) void gcn_gemm(const float* __restrict__ x,
                                                const unsigned short* __restrict__ wsW,
                                                unsigned short* __restrict__ h_s) {
    const int tid  = threadIdx.x;
    const int lane = tid & 63;
    const int wid  = tid >> 6;
    const int row0 = blockIdx.x * 128;
    const int lr = lane & 15;
    const int lg = lane >> 4;

    __shared__ char smem[49152];
    float*          ldsA = (float*)smem;                      // 32 KB
    unsigned short* ldsB = (unsigned short*)(smem + 32768);   // 16 KB
    unsigned short* EP   = (unsigned short*)smem;             // epilogue reuse

    f32x4 acc[2][8];
#pragma unroll
    for (int m = 0; m < 2; ++m)
#pragma unroll
        for (int n = 0; n < 8; ++n) acc[m][n] = (f32x4)(0.0f);

    const int a_lrow_base = wid * 4 + (lane >> 4);            // + r*16
    const int b_out_base = wid * 32 + (lane >> 3);            // + r*8

    for (int c = 0; c < 4; ++c) {
#pragma unroll
        for (int r = 0; r < 4; ++r) {
            const int out = b_out_base + r * 8;
            const int cb = ((lane & 7) * 16) ^ ((out & 7) << 4);
            const char* gp = (const char*)wsW + (long)out * (DIN * 2) + c * 128 + cb;
            GLOAD16(gp, (char*)(ldsB + (wid * 32 + r * 8) * 64));
        }
#pragma unroll
        for (int r = 0; r < 8; ++r) {
            const int lrow = r * 16 + a_lrow_base;
            int grow = row0 + lrow;
            grow = grow < NODES ? grow : NODES - 1;  // clamp; never stored
            const int cb = ((lane & 15) * 16) ^ ((lrow & 7) << 4);
            const char* gp = (const char*)x + (long)grow * (DIN * 4) + c * 256 + cb;
            GLOAD16(gp, (char*)(ldsA + (r * 16 + wid * 4) * 64));
        }
        __syncthreads();   // drains vmcnt: LDS tiles ready

#pragma unroll
        for (int ks = 0; ks < 2; ++ks) {
            s16x8 a[2], b[8];
#pragma unroll
            for (int m = 0; m < 2; ++m) {
                const int row = wid * 32 + m * 16 + lr;
                const int swz = (row & 7) << 4;
                const int b0 = (ks * 128 + lg * 32) ^ swz;
                const int b1 = (ks * 128 + lg * 32 + 16) ^ swz;
                const f32x4 p0 = *reinterpret_cast<const f32x4*>((const char*)(ldsA + row * 64) + b0);
                const f32x4 p1 = *reinterpret_cast<const f32x4*>((const char*)(ldsA + row * 64) + b1);
                s16x8 t;
                t[0] = (short)f2bf(p0[0]); t[1] = (short)f2bf(p0[1]);
                t[2] = (short)f2bf(p0[2]); t[3] = (short)f2bf(p0[3]);
                t[4] = (short)f2bf(p1[0]); t[5] = (short)f2bf(p1[1]);
                t[6] = (short)f2bf(p1[2]); t[7] = (short)f2bf(p1[3]);
                a[m] = t;
            }
#pragma unroll
            for (int n = 0; n < 8; ++n) {
                const int out = n * 16 + lr;
                const int bb = (ks * 64 + lg * 16) ^ ((out & 7) << 4);
                b[n] = *reinterpret_cast<const s16x8*>((const char*)(ldsB + out * 64) + bb);
            }
#pragma unroll
            for (int n = 0; n < 8; ++n) {
                acc[0][n] = __builtin_amdgcn_mfma_f32_16x16x32_bf16(a[0], b[n], acc[0][n], 0, 0, 0);
                acc[1][n] = __builtin_amdgcn_mfma_f32_16x16x32_bf16(a[1], b[n], acc[1][n], 0, 0, 0);
            }
        }
        __syncthreads();   // LDS reads done before next chunk overwrites
    }

    // epilogue: acc -> EP (padded) -> row-linear 16B dense stores
#pragma unroll
    for (int m = 0; m < 2; ++m) {
#pragma unroll
        for (int n = 0; n < 8; ++n) {
#pragma unroll
            for (int r = 0; r < 4; ++r) {
                const int rl = wid * 32 + m * 16 + lg * 4 + r;
                EP[rl * EW + n * 16 + lr] = f2bf(acc[m][n][r]);
            }
        }
    }
    __syncthreads();
#pragma unroll
    for (int p = 0; p < 8; ++p) {
        const int rl  = p * 16 + (tid >> 4);
        const int ch0 = (tid & 15) * 8;
        const int row = row0 + rl;
        if (row < NODES) {
            const s16x8 v = *reinterpret_cast<const s16x8*>(EP + rl * EW + ch0);
            const long sb = (long)(ch0 >> 6) * ((long)SROW * SLICE_CH);
            *reinterpret_cast<s16x8*>(h_s + sb + (long)row * SLICE_CH + (ch0 & 63)) = v;
        }
    }
}

// ---------------- Aggregation: 2 slices x 64ch, explicit MLP=16 -------------
// R15 (MLP=8) total-best. Gather is latency/refill-bound (FETCH 153MB @
// ~3TB/s), so depth is the lever: 2 super-groups x {compute 16 clamped srcs
// (shfl-only), issue 16 independent u32x4 gathers into named regs, then
// accumulate}. ~16 loads in flight (~64 data VGPR + addrs; launch_bounds
// (320,2) keeps 2 blocks/CU). Group index e>>3 = eg*2+(j>>3) compile-time
// (rule #20).
__global__ __launch_bounds__(320, 2) void gcn_agg(const int* __restrict__ ptr,
                                                  const int* __restrict__ idx,
                                                  const unsigned short* __restrict__ h_s,
                                                  const float* __restrict__ inv_deg,
                                                  float* __restrict__ out, int E) {
    const int lane  = threadIdx.x & 63;
    const int wid   = threadIdx.x >> 6;               // 0..4
    const int q     = blockIdx.x & 7;                 // XCD id
    const int slice = q >> 2;                         // 0..1
    const int chunk = (blockIdx.x >> 3) * 4 + (q & 3);  // 0..2499
    const int g     = lane >> 3;                      // node sub-index 0..7
    const int c     = lane & 7;                       // eighth-row 0..7
    const int node  = chunk * 40 + wid * 8 + g;       // 2500*40 = 100000

    const int p0  = ptr[node];
    const int deg = ptr[node + 1] - p0;
    const int Em1 = E - 1;
    const float w = inv_deg[node];

    // preload edge indices: lane c holds edges {c, c+8, c+16, c+24} of node g
    int r[4];
#pragma unroll
    for (int j = 0; j < 4; ++j) {
        int a = p0 + c + 8 * j;
        a = a < Em1 ? a : Em1;
        r[j] = idx[a];
    }

    const unsigned short* hb = h_s + (long)slice * ((long)SROW * SLICE_CH) + c * 8;

    float a0 = 0.f, a1 = 0.f, a2 = 0.f, a3 = 0.f;
    float a4 = 0.f, a5 = 0.f, a6 = 0.f, a7 = 0.f;

#pragma unroll
    for (int eg = 0; eg < 2; ++eg) {
        // 16 srcs of this super-group (zero-row clamp -> unconditional loads)
        int ss[16];
#pragma unroll
        for (int j = 0; j < 16; ++j) {
            const int e = eg * 16 + j;
            int s = __shfl(r[eg * 2 + (j >> 3)], (lane & 56) | (j & 7));
            ss[j] = e < deg ? s : NODES;
        }
        // 16 independent gathers in flight
        u32x4 v0  = *reinterpret_cast<const u32x4*>(hb + (long)ss[0]  * SLICE_CH);
        u32x4 v1  = *reinterpret_cast<const u32x4*>(hb + (long)ss[1]  * SLICE_CH);
        u32x4 v2  = *reinterpret_cast<const u32x4*>(hb + (long)ss[2]  * SLICE_CH);
        u32x4 v3  = *reinterpret_cast<const u32x4*>(hb + (long)ss[3]  * SLICE_CH);
        u32x4 v4  = *reinterpret_cast<const u32x4*>(hb + (long)ss[4]  * SLICE_CH);
        u32x4 v5  = *reinterpret_cast<const u32x4*>(hb + (long)ss[5]  * SLICE_CH);
        u32x4 v6  = *reinterpret_cast<const u32x4*>(hb + (long)ss[6]  * SLICE_CH);
        u32x4 v7  = *reinterpret_cast<const u32x4*>(hb + (long)ss[7]  * SLICE_CH);
        u32x4 v8  = *reinterpret_cast<const u32x4*>(hb + (long)ss[8]  * SLICE_CH);
        u32x4 v9  = *reinterpret_cast<const u32x4*>(hb + (long)ss[9]  * SLICE_CH);
        u32x4 v10 = *reinterpret_cast<const u32x4*>(hb + (long)ss[10] * SLICE_CH);
        u32x4 v11 = *reinterpret_cast<const u32x4*>(hb + (long)ss[11] * SLICE_CH);
        u32x4 v12 = *reinterpret_cast<const u32x4*>(hb + (long)ss[12] * SLICE_CH);
        u32x4 v13 = *reinterpret_cast<const u32x4*>(hb + (long)ss[13] * SLICE_CH);
        u32x4 v14 = *reinterpret_cast<const u32x4*>(hb + (long)ss[14] * SLICE_CH);
        u32x4 v15 = *reinterpret_cast<const u32x4*>(hb + (long)ss[15] * SLICE_CH);
#define ACC(V) { a0 += lo2f(V[0]); a1 += hi2f(V[0]); a2 += lo2f(V[1]); a3 += hi2f(V[1]); \
                 a4 += lo2f(V[2]); a5 += hi2f(V[2]); a6 += lo2f(V[3]); a7 += hi2f(V[3]); }
        ACC(v0); ACC(v1); ACC(v2);  ACC(v3);  ACC(v4);  ACC(v5);  ACC(v6);  ACC(v7);
        ACC(v8); ACC(v9); ACC(v10); ACC(v11); ACC(v12); ACC(v13); ACC(v14); ACC(v15);
#undef ACC
    }

    float* op = out + (long)node * DOUT + slice * SLICE_CH + c * 8;
    f32x4 o0, o1;
    o0[0] = a0 * w; o0[1] = a1 * w; o0[2] = a2 * w; o0[3] = a3 * w;
    o1[0] = a4 * w; o1[1] = a5 * w; o1[2] = a6 * w; o1[3] = a7 * w;
    *reinterpret_cast<f32x4*>(op) = o0;
    *reinterpret_cast<f32x4*>(op + 4) = o1;
}

extern "C" void kernel_launch(void* const* d_in, const int* in_sizes, int n_in,
                              void* d_out, int out_size, void* d_ws, size_t ws_size,
                              hipStream_t stream) {
    const float* x   = (const float*)d_in[0];
    const float* W   = (const float*)d_in[1];
    const int*   ptr = (const int*)d_in[2];
    const int*   idx = (const int*)d_in[3];
    // d_in[4] (dst) unused: CSR ptr encodes destinations.
    float* out = (float*)d_out;
    const int E = in_sizes[3];

    char* ws = (char*)d_ws;
    unsigned short* wsW     = (unsigned short*)ws;               // 64 KB
    float*          inv_deg = (float*)(ws + (64 << 10));         // 400 KB
    unsigned short* h_s     = (unsigned short*)(ws + (1 << 20)); // 2*SROW*64*2B

    gcn_prep<<<391, 256, 0, stream>>>(W, ptr, wsW, inv_deg, h_s);
    // 782 blocks x (128x128) tile; 4 waves/block, global_load_lds staging
    gcn_gemm<<<782, 256, 0, stream>>>(x, wsW, h_s);
    // 625 x 8 blocks: XCD q=blockIdx&7 -> slice q>>2, chunk=(blockIdx>>3)*4+(q&3)
    gcn_agg<<<5000, 320, 0, stream>>>(ptr, idx, h_s, inv_deg, out, E);
}

// Round 17
// 86.773 us; speedup vs baseline: 1.0132x; 1.0132x over previous
//
#include <hip/hip_runtime.h>
#include <hip/hip_bf16.h>

typedef __attribute__((ext_vector_type(4))) float f32x4;
typedef __attribute__((ext_vector_type(8))) short s16x8;
typedef __attribute__((ext_vector_type(4))) unsigned int u32x4;

#define NODES 100000
#define SROW (NODES + 1)   // +1 zero row per slice: predication-free gathers
#define DIN 256
#define DOUT 128
#define NSLICE 2
#define SLICE_CH 64        // h_s[slice][SROW][64] bf16 = 12.8 MB/slice
#define EW 136             // epilogue LDS row stride (128 + 8 pad shorts)

static __device__ inline unsigned short f2bf(float f) {
    __hip_bfloat16 h = __float2bfloat16(f);
    return __builtin_bit_cast(unsigned short, h);
}
static __device__ inline float lo2f(unsigned int v) {  // low bf16 -> f32
    return __builtin_bit_cast(float, v << 16);
}
static __device__ inline float hi2f(unsigned int v) {  // high bf16 -> f32
    return __builtin_bit_cast(float, v & 0xffff0000u);
}

// async global->LDS, 16B per lane. Dest must be wave-uniform; source is
// per-lane (pre-swizzled source = rule-21 both-sides involution).
#define GLOAD16(GP, LP) \
    __builtin_amdgcn_global_load_lds( \
        (const __attribute__((address_space(1))) void*)(GP), \
        (__attribute__((address_space(3))) void*)(LP), 16, 0, 0)

// ---------------- prep: W fp32 -> bf16 ; inv_deg ; zero rows ----------------
__global__ __launch_bounds__(256) void gcn_prep(const float* __restrict__ W,
                                                const int* __restrict__ ptr,
                                                unsigned short* __restrict__ wsW,
                                                float* __restrict__ inv_deg,
                                                unsigned short* __restrict__ h_s) {
    int t = blockIdx.x * 256 + threadIdx.x;
    if (t < DOUT * DIN) wsW[t] = f2bf(W[t]);
    if (t < NODES) {
        int d = ptr[t + 1] - ptr[t];
        inv_deg[t] = d > 0 ? 1.0f / (float)d : 0.0f;
    }
    if (t < NSLICE * SLICE_CH)  // zero row (node index NODES) of each slice
        h_s[(long)(t >> 6) * ((long)SROW * SLICE_CH) + (long)NODES * SLICE_CH + (t & 63)] = 0;
}

// ---------------- GEMM: h_s[slice][SROW][64] (bf16) = x @ W.T ---------------
// (Best-known structure, unchanged: global_load_lds staging, B staged first
// (L2-hot, retires under A's HBM latency), pre-swizzled source + swizzled
// fragment reads, involution byte16-slot ^= ((row&7)<<4). ~24-26us measured;
// x-read HBM floor is ~20us.)
__global__ __launch_bounds__(256) void gcn_gemm(const float* __restrict__ x,
                                                const unsigned short* __restrict__ wsW,
                                                unsigned short* __restrict__ h_s) {
    const int tid  = threadIdx.x;
    const int lane = tid & 63;
    const int wid  = tid >> 6;
    const int row0 = blockIdx.x * 128;
    const int lr = lane & 15;
    const int lg = lane >> 4;

    __shared__ char smem[49152];
    float*          ldsA = (float*)smem;                      // 32 KB
    unsigned short* ldsB = (unsigned short*)(smem + 32768);   // 16 KB
    unsigned short* EP   = (unsigned short*)smem;             // epilogue reuse

    f32x4 acc[2][8];
#pragma unroll
    for (int m = 0; m < 2; ++m)
#pragma unroll
        for (int n = 0; n < 8; ++n) acc[m][n] = (f32x4)(0.0f);

    const int a_lrow_base = wid * 4 + (lane >> 4);            // + r*16
    const int b_out_base = wid * 32 + (lane >> 3);            // + r*8

    for (int c = 0; c < 4; ++c) {
#pragma unroll
        for (int r = 0; r < 4; ++r) {
            const int out = b_out_base + r * 8;
            const int cb = ((lane & 7) * 16) ^ ((out & 7) << 4);
            const char* gp = (const char*)wsW + (long)out * (DIN * 2) + c * 128 + cb;
            GLOAD16(gp, (char*)(ldsB + (wid * 32 + r * 8) * 64));
        }
#pragma unroll
        for (int r = 0; r < 8; ++r) {
            const int lrow = r * 16 + a_lrow_base;
            int grow = row0 + lrow;
            grow = grow < NODES ? grow : NODES - 1;  // clamp; never stored
            const int cb = ((lane & 15) * 16) ^ ((lrow & 7) << 4);
            const char* gp = (const char*)x + (long)grow * (DIN * 4) + c * 256 + cb;
            GLOAD16(gp, (char*)(ldsA + (r * 16 + wid * 4) * 64));
        }
        __syncthreads();   // drains vmcnt: LDS tiles ready

#pragma unroll
        for (int ks = 0; ks < 2; ++ks) {
            s16x8 a[2], b[8];
#pragma unroll
            for (int m = 0; m < 2; ++m) {
                const int row = wid * 32 + m * 16 + lr;
                const int swz = (row & 7) << 4;
                const int b0 = (ks * 128 + lg * 32) ^ swz;
                const int b1 = (ks * 128 + lg * 32 + 16) ^ swz;
                const f32x4 p0 = *reinterpret_cast<const f32x4*>((const char*)(ldsA + row * 64) + b0);
                const f32x4 p1 = *reinterpret_cast<const f32x4*>((const char*)(ldsA + row * 64) + b1);
                s16x8 t;
                t[0] = (short)f2bf(p0[0]); t[1] = (short)f2bf(p0[1]);
                t[2] = (short)f2bf(p0[2]); t[3] = (short)f2bf(p0[3]);
                t[4] = (short)f2bf(p1[0]); t[5] = (short)f2bf(p1[1]);
                t[6] = (short)f2bf(p1[2]); t[7] = (short)f2bf(p1[3]);
                a[m] = t;
            }
#pragma unroll
            for (int n = 0; n < 8; ++n) {
                const int out = n * 16 + lr;
                const int bb = (ks * 64 + lg * 16) ^ ((out & 7) << 4);
                b[n] = *reinterpret_cast<const s16x8*>((const char*)(ldsB + out * 64) + bb);
            }
#pragma unroll
            for (int n = 0; n < 8; ++n) {
                acc[0][n] = __builtin_amdgcn_mfma_f32_16x16x32_bf16(a[0], b[n], acc[0][n], 0, 0, 0);
                acc[1][n] = __builtin_amdgcn_mfma_f32_16x16x32_bf16(a[1], b[n], acc[1][n], 0, 0, 0);
            }
        }
        __syncthreads();   // LDS reads done before next chunk overwrites
    }

    // epilogue: acc -> EP (padded) -> row-linear 16B dense stores
#pragma unroll
    for (int m = 0; m < 2; ++m) {
#pragma unroll
        for (int n = 0; n < 8; ++n) {
#pragma unroll
            for (int r = 0; r < 4; ++r) {
                const int rl = wid * 32 + m * 16 + lg * 4 + r;
                EP[rl * EW + n * 16 + lr] = f2bf(acc[m][n][r]);
            }
        }
    }
    __syncthreads();
#pragma unroll
    for (int p = 0; p < 8; ++p) {
        const int rl  = p * 16 + (tid >> 4);
        const int ch0 = (tid & 15) * 8;
        const int row = row0 + rl;
        if (row < NODES) {
            const s16x8 v = *reinterpret_cast<const s16x8*>(EP + rl * EW + ch0);
            const long sb = (long)(ch0 >> 6) * ((long)SROW * SLICE_CH);
            *reinterpret_cast<s16x8*>(h_s + sb + (long)row * SLICE_CH + (ch0 & 63)) = v;
        }
    }
}

// ---------------- Aggregation: 2 slices x 64ch, explicit MLP=8 --------------
// (R15 structure, the best measured total. 4 groups x {compute 8 srcs
// (shfl-only), issue 8 independent u32x4 gathers into named regs, then
// accumulate}. MLP=16 (R16) was neutral: compiler capped VGPR at 56, depth
// stayed ~8 -> MLP saturated against the L2-transaction/HBM-refill floor.
// Zero-row padded gathers coalesce (same hot line) -> near-free.)
__global__ __launch_bounds__(320, 2) void gcn_agg(const int* __restrict__ ptr,
                                                  const int* __restrict__ idx,
                                                  const unsigned short* __restrict__ h_s,
                                                  const float* __restrict__ inv_deg,
                                                  float* __restrict__ out, int E) {
    const int lane  = threadIdx.x & 63;
    const int wid   = threadIdx.x >> 6;               // 0..4
    const int q     = blockIdx.x & 7;                 // XCD id
    const int slice = q >> 2;                         // 0..1
    const int chunk = (blockIdx.x >> 3) * 4 + (q & 3);  // 0..2499
    const int g     = lane >> 3;                      // node sub-index 0..7
    const int c     = lane & 7;                       // eighth-row 0..7
    const int node  = chunk * 40 + wid * 8 + g;       // 2500*40 = 100000

    const int p0  = ptr[node];
    const int deg = ptr[node + 1] - p0;
    const int Em1 = E - 1;
    const float w = inv_deg[node];

    // preload edge indices: lane c holds edges {c, c+8, c+16, c+24} of node g
    int r[4];
#pragma unroll
    for (int j = 0; j < 4; ++j) {
        int a = p0 + c + 8 * j;
        a = a < Em1 ? a : Em1;
        r[j] = idx[a];
    }

    const unsigned short* hb = h_s + (long)slice * ((long)SROW * SLICE_CH) + c * 8;

    float a0 = 0.f, a1 = 0.f, a2 = 0.f, a3 = 0.f;
    float a4 = 0.f, a5 = 0.f, a6 = 0.f, a7 = 0.f;

#pragma unroll
    for (int eg = 0; eg < 4; ++eg) {
        // 8 srcs of this group (zero-row clamp -> unconditional loads)
        int ss[8];
#pragma unroll
        for (int j = 0; j < 8; ++j) {
            const int e = eg * 8 + j;
            int s = __shfl(r[eg], (lane & 56) | j);
            ss[j] = e < deg ? s : NODES;
        }
        // 8 independent gathers in flight
        u32x4 v0 = *reinterpret_cast<const u32x4*>(hb + (long)ss[0] * SLICE_CH);
        u32x4 v1 = *reinterpret_cast<const u32x4*>(hb + (long)ss[1] * SLICE_CH);
        u32x4 v2 = *reinterpret_cast<const u32x4*>(hb + (long)ss[2] * SLICE_CH);
        u32x4 v3 = *reinterpret_cast<const u32x4*>(hb + (long)ss[3] * SLICE_CH);
        u32x4 v4 = *reinterpret_cast<const u32x4*>(hb + (long)ss[4] * SLICE_CH);
        u32x4 v5 = *reinterpret_cast<const u32x4*>(hb + (long)ss[5] * SLICE_CH);
        u32x4 v6 = *reinterpret_cast<const u32x4*>(hb + (long)ss[6] * SLICE_CH);
        u32x4 v7 = *reinterpret_cast<const u32x4*>(hb + (long)ss[7] * SLICE_CH);
#define ACC(V) { a0 += lo2f(V[0]); a1 += hi2f(V[0]); a2 += lo2f(V[1]); a3 += hi2f(V[1]); \
                 a4 += lo2f(V[2]); a5 += hi2f(V[2]); a6 += lo2f(V[3]); a7 += hi2f(V[3]); }
        ACC(v0); ACC(v1); ACC(v2); ACC(v3); ACC(v4); ACC(v5); ACC(v6); ACC(v7);
#undef ACC
    }

    float* op = out + (long)node * DOUT + slice * SLICE_CH + c * 8;
    f32x4 o0, o1;
    o0[0] = a0 * w; o0[1] = a1 * w; o0[2] = a2 * w; o0[3] = a3 * w;
    o1[0] = a4 * w; o1[1] = a5 * w; o1[2] = a6 * w; o1[3] = a7 * w;
    *reinterpret_cast<f32x4*>(op) = o0;
    *reinterpret_cast<f32x4*>(op + 4) = o1;
}

extern "C" void kernel_launch(void* const* d_in, const int* in_sizes, int n_in,
                              void* d_out, int out_size, void* d_ws, size_t ws_size,
                              hipStream_t stream) {
    const float* x   = (const float*)d_in[0];
    const float* W   = (const float*)d_in[1];
    const int*   ptr = (const int*)d_in[2];
    const int*   idx = (const int*)d_in[3];
    // d_in[4] (dst) unused: CSR ptr encodes destinations.
    float* out = (float*)d_out;
    const int E = in_sizes[3];

    char* ws = (char*)d_ws;
    unsigned short* wsW     = (unsigned short*)ws;               // 64 KB
    float*          inv_deg = (float*)(ws + (64 << 10));         // 400 KB
    unsigned short* h_s     = (unsigned short*)(ws + (1 << 20)); // 2*SROW*64*2B

    gcn_prep<<<391, 256, 0, stream>>>(W, ptr, wsW, inv_deg, h_s);
    // 782 blocks x (128x128) tile; 4 waves/block, global_load_lds staging
    gcn_gemm<<<782, 256, 0, stream>>>(x, wsW, h_s);
    // 625 x 8 blocks: XCD q=blockIdx&7 -> slice q>>2, chunk=(blockIdx>>3)*4+(q&3)
    gcn_agg<<<5000, 320, 0, stream>>>(ptr, idx, h_s, inv_deg, out, E);
}